// Round 5
// baseline (31398.950 us; speedup 1.0000x reference)
//
#include <hip/hip_runtime.h>
#include <math.h>

#define Hh   512
#define TH   1536
#define LINN 128
#define RD   16
#define NWG0 16          /* layer-0 WGs: 32 h each */
#define NWG1 32          /* layer-1 WGs: 16 h each */
#define NWG  (NWG0 + NWG1)
typedef unsigned long long ull;
typedef unsigned int u32;

#define WS_A     0
#define WS_CC    6144
#define WS_RING0 16384
#define WS_RING1 (16384 + Hh * RD * 8)
// ws usage ends at 16384 + 2*Hh*RD*8 = 147456 bytes

__device__ __forceinline__ float sigm(float v) { return 1.f / (1.f + __expf(-v)); }
__device__ __forceinline__ float tanh_fast(float x) { return 2.f / (1.f + __expf(-2.f * x)) - 1.f; }
__device__ __forceinline__ ull  pk(float v, u32 tag) { return ((ull)tag << 32) | (ull)__float_as_uint(v); }
__device__ __forceinline__ ull  ring_ld(const ull* p) {
    return __hip_atomic_load(p, __ATOMIC_RELAXED, __HIP_MEMORY_SCOPE_AGENT);
}
__device__ __forceinline__ void ring_st(ull* p, ull v) {
    __hip_atomic_store(p, v, __ATOMIC_RELAXED, __HIP_MEMORY_SCOPE_AGENT);
}

// ---------------------------------------------------------------- prep:
// A[row] = W_ih0[row,:]@W_proc ; CC[row] = W_ih0[row,:]@b_proc + b_ih0 (+ b_hh0 for r,z rows)
__global__ void prep(const float* __restrict__ Wih0, const float* __restrict__ Wproc,
                     const float* __restrict__ bproc, const float* __restrict__ bih0,
                     const float* __restrict__ bhh0, float* __restrict__ A,
                     float* __restrict__ CC)
{
    int row = blockIdx.x * 256 + threadIdx.x;
    if (row >= TH) return;
    const float* w = Wih0 + (size_t)row * LINN;
    float a = 0.f, c = 0.f;
    for (int k = 0; k < LINN; ++k) { float wv = w[k]; a = fmaf(wv, Wproc[k], a); c = fmaf(wv, bproc[k], c); }
    c += bih0[row];
    if (row < 2 * Hh) c += bhh0[row];
    A[row] = a; CC[row] = c;
}

// ---------------------------------------------------------------- ring init (tags + initial state, every call)
__global__ void ringinit(const float* __restrict__ mem, ull* __restrict__ ring0,
                         ull* __restrict__ ring1)
{
    const int t = threadIdx.x;          // 512 threads
    for (int slot = 0; slot < RD; ++slot) {
        ring0[slot * Hh + t] = pk(slot == RD - 1 ? mem[t]      : 0.f, 0u);
        ring1[slot * Hh + t] = pk(slot == RD - 1 ? mem[Hh + t] : 0.f, 0u);
    }
}

// ---------------------------------------------------------------- fused self-timed dataflow scan
// Weights in REGISTERS (statically indexed float4 arrays; 1 wave/SIMD so ~450 VGPR budget).
// WG 0..15  : layer 0, 32 h each. lane = (g=tid>>5: h-subgroup, q=tid&31: 16-wide k-chunk)
// WG 16..47 : layer 1 (lag 1), 16 h each. same lane decomposition.
// Exchange: RD-deep rings of (float|tag) 8B words, relaxed agent atomics, R3 poll form.
__launch_bounds__(256, 1)
__global__ void fused(const float* __restrict__ input, const float* __restrict__ resid,
                      const float* __restrict__ Whh0, const float* __restrict__ bhh0,
                      const float* __restrict__ A, const float* __restrict__ CC,
                      const float* __restrict__ Wih1, const float* __restrict__ Whh1,
                      const float* __restrict__ bih1, const float* __restrict__ bhh1,
                      ull* __restrict__ ring0, ull* __restrict__ ring1,
                      float* __restrict__ outp, int T)
{
    __shared__ __align__(16) float hbA[2][Hh];   // L0: h0 dbuf | L1: h0 dbuf
    __shared__ __align__(16) float hbB[2][Hh];   // L1: h1 dbuf
    const int tid = threadIdx.x;
    const int wg  = blockIdx.x;
    const int q   = tid & 31;          // k-chunk: k in [16q, 16q+16)
    const int g   = tid >> 5;          // 0..7 h-subgroup

    if (wg < NWG0) {
        // ---------------- layer 0: 4 h per lane ----------------
        const int jb = wg * 32 + g * 4;
        float4 w0[4][3][4];
#pragma unroll
        for (int m = 0; m < 4; ++m)
#pragma unroll
            for (int gt = 0; gt < 3; ++gt)
#pragma unroll
                for (int c = 0; c < 4; ++c)
                    w0[m][gt][c] = *(const float4*)&Whh0[((size_t)(gt * Hh + jb + m)) * Hh + 16 * q + 4 * c];
        float Ar[4], Az[4], An[4], Cr[4], Cz[4], Cn[4], Bn[4];
#pragma unroll
        for (int m = 0; m < 4; ++m) {
            int j = jb + m;
            Ar[m] = A[j]; Az[m] = A[j + Hh]; An[m] = A[j + 2 * Hh];
            Cr[m] = CC[j]; Cz[m] = CC[j + Hh]; Cn[m] = CC[j + 2 * Hh];
            Bn[m] = bhh0[j + 2 * Hh];
        }

        for (int s = 0; s < T; ++s) {
            const float x = input[s];                       // issued early, consumed late
            const ull* prev = ring0 + (size_t)((s - 1) & (RD - 1)) * Hh;
            const u32 tgt = (u32)s;
            ull p0, p1;
            do { p0 = ring_ld(prev + tid);       } while ((u32)(p0 >> 32) < tgt);
            do { p1 = ring_ld(prev + tid + 256); } while ((u32)(p1 >> 32) < tgt);
            if (tid == 0 && s >= 8 && (s & 7) == 0) {       // amortized back-pressure
                const ull* bp = ring1 + (size_t)((s - 8) & (RD - 1)) * Hh;
                while ((u32)(ring_ld(bp) >> 32) < (u32)(s - 7)) {}
            }
            float* hbc = hbA[s & 1];
            hbc[tid]       = __uint_as_float((u32)p0);
            hbc[tid + 256] = __uint_as_float((u32)p1);
            __syncthreads();
            float4 hv[4];
#pragma unroll
            for (int c = 0; c < 4; ++c) hv[c] = *(const float4*)&hbc[16 * q + 4 * c];
            float acc[4][3];
#pragma unroll
            for (int m = 0; m < 4; ++m)
#pragma unroll
                for (int gt = 0; gt < 3; ++gt) {
                    float a = 0.f;
#pragma unroll
                    for (int c = 0; c < 4; ++c) {
                        const float4 w = w0[m][gt][c], h = hv[c];
                        a = fmaf(w.x, h.x, a); a = fmaf(w.y, h.y, a);
                        a = fmaf(w.z, h.z, a); a = fmaf(w.w, h.w, a);
                    }
                    acc[m][gt] = a;
                }
#pragma unroll
            for (int off = 16; off > 0; off >>= 1)
#pragma unroll
                for (int m = 0; m < 4; ++m)
#pragma unroll
                    for (int gt = 0; gt < 3; ++gt)
                        acc[m][gt] += __shfl_xor(acc[m][gt], off);
            if (q == 0) {
#pragma unroll
                for (int m = 0; m < 4; ++m) {
                    const int j = jb + m;
                    const float r  = sigm(fmaf(Ar[m], x, Cr[m]) + acc[m][0]);
                    const float z  = sigm(fmaf(Az[m], x, Cz[m]) + acc[m][1]);
                    const float n  = tanh_fast(fmaf(An[m], x, Cn[m]) + r * (acc[m][2] + Bn[m]));
                    const float hn = (1.f - z) * n + z * hbc[j];
                    ring_st(ring0 + (size_t)(s & (RD - 1)) * Hh + j, pk(hn, (u32)(s + 1)));
                    if (s == T - 1) outp[Hh + j] = hn;
                }
            }
        }
    } else {
        // ---------------- layer 1 (lag 1): 2 h per lane ----------------
        const int wg1 = wg - NWG0;
        const int jb  = wg1 * 16 + g * 2;
        float4 wih[2][3][4], whh[2][3][4];
#pragma unroll
        for (int m = 0; m < 2; ++m)
#pragma unroll
            for (int gt = 0; gt < 3; ++gt)
#pragma unroll
                for (int c = 0; c < 4; ++c) {
                    const size_t ro = ((size_t)(gt * Hh + jb + m)) * Hh + 16 * q + 4 * c;
                    wih[m][gt][c] = *(const float4*)&Wih1[ro];
                    whh[m][gt][c] = *(const float4*)&Whh1[ro];
                }
        float Br[2], Bz[2], Bin[2], Bhn[2], resl[2];
#pragma unroll
        for (int m = 0; m < 2; ++m) {
            int j = jb + m;
            Br[m]  = bih1[j] + bhh1[j];
            Bz[m]  = bih1[j + Hh] + bhh1[j + Hh];
            Bin[m] = bih1[j + 2 * Hh];
            Bhn[m] = bhh1[j + 2 * Hh];
            resl[m] = resid[j];
        }

        for (int u = 0; u < T; ++u) {
            const ull* b1 = ring1 + (size_t)((u - 1) & (RD - 1)) * Hh;  // h1[u-1], tag u  (pacer)
            const ull* b0 = ring0 + (size_t)(u & (RD - 1)) * Hh;        // h0[u],   tag u+1
            const u32 t1g = (u32)u, t0g = (u32)(u + 1);
            ull c0, c1, a0, a1;
            do { c0 = ring_ld(b1 + tid);       } while ((u32)(c0 >> 32) < t1g);
            do { c1 = ring_ld(b1 + tid + 256); } while ((u32)(c1 >> 32) < t1g);
            do { a0 = ring_ld(b0 + tid);       } while ((u32)(a0 >> 32) < t0g);
            do { a1 = ring_ld(b0 + tid + 256); } while ((u32)(a1 >> 32) < t0g);
            float* hc0 = hbA[u & 1];
            float* hc1 = hbB[u & 1];
            hc0[tid]       = __uint_as_float((u32)a0);
            hc0[tid + 256] = __uint_as_float((u32)a1);
            hc1[tid]       = __uint_as_float((u32)c0);
            hc1[tid + 256] = __uint_as_float((u32)c1);
            __syncthreads();
            float4 h0v[4], h1v[4];
#pragma unroll
            for (int c = 0; c < 4; ++c) {
                h0v[c] = *(const float4*)&hc0[16 * q + 4 * c];
                h1v[c] = *(const float4*)&hc1[16 * q + 4 * c];
            }
            float ax[2][3], ah[2][3];
#pragma unroll
            for (int m = 0; m < 2; ++m)
#pragma unroll
                for (int gt = 0; gt < 3; ++gt) {
                    float s1 = 0.f, s2 = 0.f;
#pragma unroll
                    for (int c = 0; c < 4; ++c) {
                        const float4 wi = wih[m][gt][c], wh = whh[m][gt][c];
                        const float4 x0 = h0v[c], x1 = h1v[c];
                        s1 = fmaf(wi.x, x0.x, s1); s1 = fmaf(wi.y, x0.y, s1);
                        s1 = fmaf(wi.z, x0.z, s1); s1 = fmaf(wi.w, x0.w, s1);
                        s2 = fmaf(wh.x, x1.x, s2); s2 = fmaf(wh.y, x1.y, s2);
                        s2 = fmaf(wh.z, x1.z, s2); s2 = fmaf(wh.w, x1.w, s2);
                    }
                    ax[m][gt] = s1; ah[m][gt] = s2;
                }
#pragma unroll
            for (int off = 16; off > 0; off >>= 1)
#pragma unroll
                for (int m = 0; m < 2; ++m)
#pragma unroll
                    for (int gt = 0; gt < 3; ++gt) {
                        ax[m][gt] += __shfl_xor(ax[m][gt], off);
                        ah[m][gt] += __shfl_xor(ah[m][gt], off);
                    }
            if (q == 0) {
#pragma unroll
                for (int m = 0; m < 2; ++m) {
                    const int j = jb + m;
                    const float r   = sigm(ax[m][0] + ah[m][0] + Br[m]);
                    const float z   = sigm(ax[m][1] + ah[m][1] + Bz[m]);
                    const float n   = tanh_fast(ax[m][2] + Bin[m] + r * (ah[m][2] + Bhn[m]));
                    const float h1n = (1.f - z) * n + z * hc1[j];
                    ring_st(ring1 + (size_t)(u & (RD - 1)) * Hh + j, pk(h1n, (u32)(u + 1)));
                    resl[m] = sigm(resl[m] + h1n);
                    if (u == T - 1) { outp[j] = resl[m]; outp[2 * Hh + j] = h1n; }
                }
            }
        }
    }
}

// ---------------------------------------------------------------- host
extern "C" void kernel_launch(void* const* d_in, const int* in_sizes, int n_in,
                              void* d_out, int out_size, void* d_ws, size_t ws_size,
                              hipStream_t stream)
{
    const float* input    = (const float*)d_in[0];
    const float* residual = (const float*)d_in[1];
    const float* memory   = (const float*)d_in[2];
    const float* Wproc    = (const float*)d_in[3];
    const float* bproc    = (const float*)d_in[4];
    const float* Wih0     = (const float*)d_in[5];
    const float* Whh0     = (const float*)d_in[6];
    const float* bih0     = (const float*)d_in[7];
    const float* bhh0     = (const float*)d_in[8];
    const float* Wih1     = (const float*)d_in[9];
    const float* Whh1     = (const float*)d_in[10];
    const float* bih1     = (const float*)d_in[11];
    const float* bhh1     = (const float*)d_in[12];
    const int L = in_sizes[0];
    const int T = L - 1;
    float* out = (float*)d_out;
    char* ws = (char*)d_ws;

    float* A     = (float*)(ws + WS_A);
    float* CC    = (float*)(ws + WS_CC);
    ull*   ring0 = (ull*)(ws + WS_RING0);
    ull*   ring1 = (ull*)(ws + WS_RING1);

    prep<<<dim3((TH + 255) / 256), dim3(256), 0, stream>>>(Wih0, Wproc, bproc, bih0, bhh0, A, CC);
    ringinit<<<dim3(1), dim3(512), 0, stream>>>(memory, ring0, ring1);
    fused<<<dim3(NWG), dim3(256), 0, stream>>>(input, residual, Whh0, bhh0, A, CC,
                                               Wih1, Whh1, bih1, bhh1,
                                               ring0, ring1, out, T);
}